// Round 4
// baseline (68.477 us; speedup 1.0000x reference)
//
#include <hip/hip_runtime.h>
#include <hip/hip_fp16.h>
#include <math.h>

#define EPSF 1e-15f
#define MAX_TANH_F (1.0f - 1e-5f)
#define KDIM 512
#define NOUT 256

typedef __attribute__((ext_vector_type(8))) __bf16 bf16x8;
typedef __attribute__((ext_vector_type(4))) float f32x4;

__device__ __forceinline__ float artanh_clip(float x) {
    x = fminf(fmaxf(x, -MAX_TANH_F), MAX_TANH_F);
    return atanhf(x);
}

__device__ __forceinline__ void unpack2h(unsigned int u, float& a, float& b) {
    __half2 h = __builtin_bit_cast(__half2, u);
    a = __low2float(h);
    b = __high2float(h);
}

// P2: Wp[s][nt][lane][8] bf16 B-fragment layout (col=nt*16+(lane&15), k=s*32+(lane>>4)*8+j)
__global__ __launch_bounds__(64) void prep_w_kernel(
    const float* __restrict__ W, unsigned int* __restrict__ Wp)
{
    const int b = blockIdx.x;       // b = s*16 + nt, 256 blocks
    const int l = threadIdx.x;      // 64 lanes
    const int k0 = (b >> 4) * 32 + (l >> 4) * 8;
    const int col = (b & 15) * 16 + (l & 15);
    bf16x8 v;
    #pragma unroll
    for (int j = 0; j < 8; ++j) v[j] = (__bf16)W[(size_t)(k0 + j) * NOUT + col];
    *(uint4*)(Wp + ((size_t)b * 64 + l) * 4) = __builtin_bit_cast(uint4, v);
}

// K1: fused prep+GEMM+mobius_matvec. Block = 16 rows x 256 cols; each of the
// 4 waves owns a 64-col quarter (4 MFMA/k-step). Cross-wave row-norm via LDS.
__global__ __launch_bounds__(256) void gemm_mobius_kernel(
    const float* __restrict__ feat, const uint4* __restrict__ Wp,
    __half* __restrict__ h, float* __restrict__ hnorm2,
    float scale, int N)
{
    __shared__ float sred[4][16];
    __shared__ float sxn2[16];
    __shared__ float sfac[16];

    const int wave = threadIdx.x >> 6;
    const int lane = threadIdx.x & 63;
    const int base = blockIdx.x * 16;

    f32x4 acc[4];
    #pragma unroll
    for (int t = 0; t < 4; ++t) acc[t] = (f32x4){0.f, 0.f, 0.f, 0.f};

    const int r15 = lane & 15;
    const int g   = lane >> 4;
    const int row = base + r15;
    const int rowc = row < N ? row : (N - 1);
    const float* fr = feat + (size_t)rowc * KDIM + g * 8;
    const uint4* wp = Wp + (size_t)wave * 4 * 64 + lane;   // this wave's 4 col-tiles

    float xs = 0.f;
    for (int s = 0; s < 16; ++s) {
        const float4* f4p = (const float4*)(fr + s * 32);
        float4 v0 = f4p[0];
        float4 v1 = f4p[1];
        v0.x *= scale; v0.y *= scale; v0.z *= scale; v0.w *= scale;
        v1.x *= scale; v1.y *= scale; v1.z *= scale; v1.w *= scale;
        xs += v0.x*v0.x + v0.y*v0.y + v0.z*v0.z + v0.w*v0.w
            + v1.x*v1.x + v1.y*v1.y + v1.z*v1.z + v1.w*v1.w;
        bf16x8 a;
        a[0] = (__bf16)v0.x; a[1] = (__bf16)v0.y; a[2] = (__bf16)v0.z; a[3] = (__bf16)v0.w;
        a[4] = (__bf16)v1.x; a[5] = (__bf16)v1.y; a[6] = (__bf16)v1.z; a[7] = (__bf16)v1.w;
        #pragma unroll
        for (int t = 0; t < 4; ++t) {
            bf16x8 b = __builtin_bit_cast(bf16x8, wp[((size_t)s * 16 + t) * 64]);
            acc[t] = __builtin_amdgcn_mfma_f32_16x16x32_bf16(a, b, acc[t], 0, 0, 0);
        }
    }

    // exact x-norm^2 per row (identical in every wave; wave 0 publishes)
    xs += __shfl_xor(xs, 16);
    xs += __shfl_xor(xs, 32);
    if (wave == 0 && lane < 16) sxn2[lane] = xs;

    // per-wave partial ||mx||^2 over this wave's 64 cols, per row
    #pragma unroll
    for (int r = 0; r < 4; ++r) {
        float p = 0.f;
        #pragma unroll
        for (int t = 0; t < 4; ++t) p += acc[t][r] * acc[t][r];
        p += __shfl_xor(p, 1);
        p += __shfl_xor(p, 2);
        p += __shfl_xor(p, 4);
        p += __shfl_xor(p, 8);
        if (r15 == 0) sred[wave][g * 4 + r] = p;
    }
    __syncthreads();

    if (threadIdx.x < 16) {
        const int r = threadIdx.x;
        const float mx2 = sred[0][r] + sred[1][r] + sred[2][r] + sred[3][r];
        const float mxn = fmaxf(sqrtf(mx2), EPSF);
        const float xn  = fmaxf(sqrtf(sxn2[r]), EPSF);
        float ttv = tanhf(mxn / xn * artanh_clip(xn));
        float fc  = ttv / mxn;
        if (mxn <= 1e-10f) { fc = 0.f; ttv = 0.f; }
        sfac[r] = fc;
        if (base + r < N) hnorm2[base + r] = ttv * ttv;
    }
    __syncthreads();

    #pragma unroll
    for (int r = 0; r < 4; ++r) {
        const int row_r = base + g * 4 + r;
        if (row_r < N) {
            const float fc = sfac[g * 4 + r];
            __half* hr = h + (size_t)row_r * NOUT + wave * 64 + r15;
            #pragma unroll
            for (int t = 0; t < 4; ++t) hr[t * 16] = __float2half(acc[t][r] * fc);
        }
    }
}

// K2: sequential mobius scan. 16 lanes per row (each lane owns 16 comps),
// 4 rows per wave; one 4-shuffle reduce per step shared by 4 rows; fp16 h.
__global__ __launch_bounds__(256) void aggregate_kernel(
    const __half* __restrict__ h, const float* __restrict__ hnorm2,
    const int* __restrict__ src, const float* __restrict__ bias,
    float* __restrict__ out, float scale, int N)
{
    const int wave = threadIdx.x >> 6;
    const int lane = threadIdx.x & 63;
    const int n0 = (blockIdx.x * 4 + wave) * 4;   // first of this wave's 4 rows
    if (n0 >= N) return;
    const int g = lane >> 4;      // row slot
    const int q = lane & 15;      // component group: comps q*16 .. q*16+15
    const int myrow = n0 + g;
    const bool rowok = myrow < N;

    // 64 src ints for the 4 rows, then per-group broadcast
    size_t smax = (size_t)N * 16 - 1;
    size_t soff = (size_t)n0 * 16 + lane;
    int sidx = src[soff <= smax ? soff : smax];
    int idx[16];
    #pragma unroll
    for (int j = 0; j < 16; ++j) idx[j] = __shfl(sidx, (lane & 48) + j);

    float y2[16];
    #pragma unroll
    for (int j = 0; j < 16; ++j) y2[j] = hnorm2[idx[j]];

    // c init from j=0
    uint4 cur0, cur1, nxt0, nxt1;
    {
        const uint4* hp = (const uint4*)(h + (size_t)idx[0] * NOUT);
        cur0 = hp[q * 2]; cur1 = hp[q * 2 + 1];
        const uint4* hp1 = (const uint4*)(h + (size_t)idx[1] * NOUT);
        nxt0 = hp1[q * 2]; nxt1 = hp1[q * 2 + 1];
    }
    float c[16];
    unpack2h(cur0.x, c[0], c[1]);   unpack2h(cur0.y, c[2], c[3]);
    unpack2h(cur0.z, c[4], c[5]);   unpack2h(cur0.w, c[6], c[7]);
    unpack2h(cur1.x, c[8], c[9]);   unpack2h(cur1.y, c[10], c[11]);
    unpack2h(cur1.z, c[12], c[13]); unpack2h(cur1.w, c[14], c[15]);
    float c2 = y2[0];

    #pragma unroll
    for (int j = 1; j < 16; ++j) {
        uint4 p0 = nxt0, p1 = nxt1;
        if (j + 1 < 16) {
            const uint4* hp = (const uint4*)(h + (size_t)idx[j + 1] * NOUT);
            nxt0 = hp[q * 2]; nxt1 = hp[q * 2 + 1];
        }
        float yv[16];
        unpack2h(p0.x, yv[0], yv[1]);   unpack2h(p0.y, yv[2], yv[3]);
        unpack2h(p0.z, yv[4], yv[5]);   unpack2h(p0.w, yv[6], yv[7]);
        unpack2h(p1.x, yv[8], yv[9]);   unpack2h(p1.y, yv[10], yv[11]);
        unpack2h(p1.z, yv[12], yv[13]); unpack2h(p1.w, yv[14], yv[15]);

        float xp = 0.f;
        #pragma unroll
        for (int i = 0; i < 16; ++i) xp = fmaf(c[i], yv[i], xp);
        xp += __shfl_xor(xp, 1);
        xp += __shfl_xor(xp, 2);
        xp += __shfl_xor(xp, 4);
        xp += __shfl_xor(xp, 8);
        const float xy = xp;

        const float A = 1.f + 2.f * xy + y2[j];
        const float B = 1.f - c2;
        const float den = fmaxf(1.f + 2.f * xy + c2 * y2[j], EPSF);
        const float inv = 1.f / den;
        #pragma unroll
        for (int i = 0; i < 16; ++i) c[i] = (fmaf(A, c[i], B * yv[i])) * inv;
        c2 = fmaxf((A * A * c2 + 2.f * A * B * xy + B * B * y2[j]) * (inv * inv), 0.f);
    }

    // rst *= scale
    #pragma unroll
    for (int i = 0; i < 16; ++i) c[i] *= scale;
    c2 *= scale * scale;

    // mobius_add(rst, bias)
    float bv[16];
    {
        const float4* bp = (const float4*)(bias + q * 16);
        float4 b0 = bp[0], b1 = bp[1], b2 = bp[2], b3 = bp[3];
        bv[0]=b0.x; bv[1]=b0.y; bv[2]=b0.z; bv[3]=b0.w;
        bv[4]=b1.x; bv[5]=b1.y; bv[6]=b1.z; bv[7]=b1.w;
        bv[8]=b2.x; bv[9]=b2.y; bv[10]=b2.z; bv[11]=b2.w;
        bv[12]=b3.x; bv[13]=b3.y; bv[14]=b3.z; bv[15]=b3.w;
    }
    float bp_ = 0.f, xp_ = 0.f;
    #pragma unroll
    for (int i = 0; i < 16; ++i) { bp_ = fmaf(bv[i], bv[i], bp_); xp_ = fmaf(c[i], bv[i], xp_); }
    bp_ += __shfl_xor(bp_, 1); xp_ += __shfl_xor(xp_, 1);
    bp_ += __shfl_xor(bp_, 2); xp_ += __shfl_xor(xp_, 2);
    bp_ += __shfl_xor(bp_, 4); xp_ += __shfl_xor(xp_, 4);
    bp_ += __shfl_xor(bp_, 8); xp_ += __shfl_xor(xp_, 8);
    const float bb = bp_, xy = xp_;

    const float A = 1.f + 2.f * xy + bb;
    const float B = 1.f - c2;
    const float den = fmaxf(1.f + 2.f * xy + c2 * bb, EPSF);
    const float inv = 1.f / den;
    float r4[16];
    #pragma unroll
    for (int i = 0; i < 16; ++i) r4[i] = fmaf(A, c[i], B * bv[i]) * inv;
    const float rn2 = fmaxf((A * A * c2 + 2.f * A * B * xy + B * B * bb) * (inv * inv), 0.f);

    // expmap0(relu(logmap0(.)))
    const float rn = fmaxf(sqrtf(rn2), EPSF);
    const float lf = artanh_clip(rn) / rn;
    float u[16];
    float up = 0.f;
    #pragma unroll
    for (int i = 0; i < 16; ++i) { u[i] = fmaxf(r4[i] * lf, 0.f); up = fmaf(u[i], u[i], up); }
    up += __shfl_xor(up, 1);
    up += __shfl_xor(up, 2);
    up += __shfl_xor(up, 4);
    up += __shfl_xor(up, 8);
    const float un = fmaxf(sqrtf(up), EPSF);
    const float ef = tanhf(un) / un;

    if (rowok) {
        float* op = out + (size_t)myrow * NOUT + q * 16;
        float4 o;
        o.x = u[0]*ef;  o.y = u[1]*ef;  o.z = u[2]*ef;  o.w = u[3]*ef;  ((float4*)op)[0] = o;
        o.x = u[4]*ef;  o.y = u[5]*ef;  o.z = u[6]*ef;  o.w = u[7]*ef;  ((float4*)op)[1] = o;
        o.x = u[8]*ef;  o.y = u[9]*ef;  o.z = u[10]*ef; o.w = u[11]*ef; ((float4*)op)[2] = o;
        o.x = u[12]*ef; o.y = u[13]*ef; o.z = u[14]*ef; o.w = u[15]*ef; ((float4*)op)[3] = o;
    }
}

extern "C" void kernel_launch(void* const* d_in, const int* in_sizes, int n_in,
                              void* d_out, int out_size, void* d_ws, size_t ws_size,
                              hipStream_t stream) {
    const float* feat   = (const float*)d_in[0];
    const float* weight = (const float*)d_in[1];
    const float* bias   = (const float*)d_in[2];
    const int*   src    = (const int*)d_in[3];

    const int OUT = in_sizes[2];            // 256
    const int IN  = in_sizes[1] / OUT;      // 512
    const int N   = in_sizes[0] / IN;       // 20000
    const int DEG = in_sizes[3] / N;        // 16
    (void)IN; (void)DEG; (void)out_size; (void)ws_size; (void)n_in;

    const float scale = 1.0f / sqrtf((float)DEG);

    // ws layout: h fp16 (N*256*2 B) | hnorm2 (N f32) | Wp (256 KB)
    char* ws = (char*)d_ws;
    __half* h     = (__half*)ws;
    float* hnorm2 = (float*)(ws + (size_t)N * NOUT * 2);
    unsigned int* Wp = (unsigned int*)(ws + (size_t)N * NOUT * 2 + (size_t)N * 4);

    float* out = (float*)d_out;

    const int nrt = (N + 15) / 16;          // 1250

    hipLaunchKernelGGL(prep_w_kernel, dim3(256), dim3(64), 0, stream,
                       weight, Wp);
    hipLaunchKernelGGL(gemm_mobius_kernel, dim3(nrt), dim3(256), 0, stream,
                       feat, (const uint4*)Wp, h, hnorm2, scale, N);
    hipLaunchKernelGGL(aggregate_kernel, dim3((N + 15) / 16), dim3(256), 0, stream,
                       h, hnorm2, src, bias, out, scale, N);
}